// Round 7
// baseline (109.079 us; speedup 1.0000x reference)
//
#include <hip/hip_runtime.h>

#define NQ 10
#define NG 4
#define QD 6
#define NBATCH 1024

// 2^10 = 1024 amps. One WAVE handles ONE real component (re or im) of one
// circuit: 64 lanes x 16 scalar floats. All post-init gates are real (RY+CZ),
// so re/im evolve independently; they couple only at init (complex product,
// computed by the even wave, im half shipped via LDS) and at the final
// expectations (partials added via LDS).
// Flat index i: bit p (LSB) <-> wire q = 9-p (wire 0 = MSB, PennyLane order).
// i = lane*16 + j : bits 0..3 <- j (intra-lane), bits 4..9 <- lane bits 0..5.
// Block = 4 waves = 2 circuits x {re,im}; grid 2048; launch_bounds(256,8)
// targets 8 waves/SIMD (VGPR<=64).

typedef unsigned u2v __attribute__((ext_vector_type(2)));

// ---------- DPP helpers ----------
template<int CTRL, int RM, int BM, bool BC>
__device__ __forceinline__ float dppmov(float x) {
    return __int_as_float(__builtin_amdgcn_update_dpp(
        0, __float_as_int(x), CTRL, RM, BM, BC));
}
// fetch DPPs: full permutations, bound_ctrl=1 (no old operand, combinable)
template<int CTRL>
__device__ __forceinline__ float dpp1(float x) { return dppmov<CTRL,0xF,0xF,true>(x); }
// xor1 = quad_perm{1,0,3,2}=0xB1; xor2 = quad_perm{2,3,0,1}=0x4E;
// xor4 = row_half_mirror(^7)=0x141 then quad_perm{3,2,1,0}(^3)=0x1B;
// xor8 = row_ror:8 = 0x128. (all validated R6)

struct FX1 { static __device__ __forceinline__ float f(float x){ return dpp1<0xB1>(x); } };
struct FX2 { static __device__ __forceinline__ float f(float x){ return dpp1<0x4E>(x); } };
struct FX4 { static __device__ __forceinline__ float f(float x){ return dpp1<0x1B>(dpp1<0x141>(x)); } };
struct FX8 { static __device__ __forceinline__ float f(float x){ return dpp1<0x128>(x); } };
// fallbacks if permlane-swap builtins unavailable
struct FX16 {
    static __device__ __forceinline__ float f(float x){
        return __int_as_float(__builtin_amdgcn_ds_swizzle(__float_as_int(x), 0x401F));
    }
};
struct FX32 {
    static __device__ __forceinline__ float f(float x){ return __shfl_xor(x, 32, 64); }
};

__device__ __forceinline__ float rlane(float v, int idx) {
    return __int_as_float(__builtin_amdgcn_readlane(__float_as_int(v), idx));
}

// ---------- gfx950 permlane swap transposes (validated R6) ----------
#if __has_builtin(__builtin_amdgcn_permlane32_swap) && __has_builtin(__builtin_amdgcn_permlane16_swap)
#define HAVE_SWAP 1
__device__ __forceinline__ void plswap32(float &a, float &b) {
    u2v r = __builtin_amdgcn_permlane32_swap(__float_as_uint(a), __float_as_uint(b), false, false);
    a = __uint_as_float(r.x); b = __uint_as_float(r.y);
}
__device__ __forceinline__ void plswap16(float &a, float &b) {
    u2v r = __builtin_amdgcn_permlane16_swap(__float_as_uint(a), __float_as_uint(b), false, false);
    a = __uint_as_float(r.x); b = __uint_as_float(r.y);
}
// transpose lane-bit5 <-> reg-bit3
__device__ __forceinline__ void tr_b5b3(float (&s)[16]) {
#pragma unroll
    for (int j = 0; j < 8; ++j) plswap32(s[j], s[j + 8]);
}
// transpose lane-bit4 <-> reg-bit2
__device__ __forceinline__ void tr_b4b2(float (&s)[16]) {
#pragma unroll
    for (int jj = 0; jj < 8; ++jj) {
        const int j = (jj & 3) | ((jj >> 2) << 3);   // 0,1,2,3,8,9,10,11
        plswap16(s[j], s[j + 4]);
    }
}
#else
#define HAVE_SWAP 0
#endif

// wave-wide sum broadcast (validated R3/R4/R6)
__device__ __forceinline__ float wave_reduce(float x) {
    x += dppmov<0x111,0xF,0xF,true >(x);   // row_shr:1
    x += dppmov<0x112,0xF,0xF,true >(x);   // row_shr:2
    x += dppmov<0x114,0xF,0xF,true >(x);   // row_shr:4
    x += dppmov<0x118,0xF,0xF,true >(x);   // row_shr:8
    x += dppmov<0x142,0xA,0xF,false>(x);   // row_bcast15
    x += dppmov<0x143,0xC,0xF,false>(x);   // row_bcast31
    return __int_as_float(__builtin_amdgcn_readlane(__float_as_int(x), 63));
}

template<int M>
__device__ __forceinline__ void intra_rot(float (&s)[16], float c, float sn) {
#pragma unroll
    for (int j = 0; j < 16; ++j)
        if ((j & M) == 0) {
            const int k = j | M;
            float v0 = s[j], v1 = s[k];
            s[j] = v0 * c - v1 * sn;
            s[k] = v0 * sn + v1 * c;
        }
}

// x' = c*x + sv*partner, sv = +-s by lane bit (R1-validated sign convention)
template<class PF, int LM>
__device__ __forceinline__ void cross_rot(float (&s)[16], float c, float sn, int lane) {
    const float sv = (lane & LM) ? sn : -sn;
#pragma unroll
    for (int j = 0; j < 16; ++j) {
        float p = PF::f(s[j]);
        s[j] = c * s[j] + sv * p;
    }
}

template<class PF>
__device__ __forceinline__ float cross_exp(const float (&s)[16]) {
    float a = 0.f;
#pragma unroll
    for (int j = 0; j < 16; ++j) a += s[j] * PF::f(s[j]);
    return a;
}

template<int M>
__device__ __forceinline__ float intra_exp(const float (&s)[16]) {
    float a = 0.f;
#pragma unroll
    for (int j = 0; j < 16; ++j) a += s[j] * s[j ^ M];
    return a;
}

__global__ __launch_bounds__(256, 8) void qsim_kernel(
    const float* __restrict__ noise,     // (NBATCH, NQ)
    const float* __restrict__ qp,        // (NG, QD, NQ)
    float* __restrict__ out)             // (NBATCH, NG*NQ)
{
    __shared__ float ship[2][1024];      // im half of init state per circuit
    __shared__ float partlds[2][16];     // expectation partials (10 used)

    const int tid  = threadIdx.x;
    const int wave = tid >> 6;
    const int lane = tid & 63;
    const int pc   = wave >> 1;                       // circuit within block
    const int comp = wave & 1;                        // 0 = re, 1 = im
    const int g    = blockIdx.x & 3;                  // block-uniform
    const int b    = (blockIdx.x >> 2) * 2 + pc;      // batch index

    // ---- weight angles: lane-parallel sincos once, readlane per layer ----
    float wcv, wsv;
    {
        const int widx = (lane < QD * NQ) ? lane : 0;
        __sincosf(0.5f * qp[g * (QD * NQ) + widx], &wsv, &wcv);
    }

    float s[16];

    // ---- init: even wave computes complex product state, ships im via LDS --
    if (comp == 0) {
        float nc[NQ], ns[NQ];
#pragma unroll
        for (int q = 0; q < NQ; ++q)
            __sincosf(0.5f * noise[b * NQ + q], &ns[q], &nc[q]);

        // per-qubit factor of RX(t)RY(t)|0>: bit=0 -> (c^2,-s^2), bit=1 -> (cs,-cs)
        auto facr = [&](int q, int bit) { return bit ? nc[q]*ns[q] : nc[q]*nc[q]; };
        auto faci = [&](int q, int bit) { return bit ? -nc[q]*ns[q] : -ns[q]*ns[q]; };

        // lane-determined product over lane bits 0..5 (wires 5..0)
        float hr = 1.f, hi = 0.f;
#pragma unroll
        for (int p = 4; p <= 9; ++p) {
            const int q = NQ - 1 - p, bit = (lane >> (p - 4)) & 1;
            float fr = facr(q, bit), fi = faci(q, bit);
            float tr = hr * fr - hi * fi;
            float ti = hr * fi + hi * fr;
            hr = tr; hi = ti;
        }
        // factor tree over reg bits: t01 = wires 9,8 ; t23 = wires 7,6
        float t01r[4], t01i[4], t23r[4], t23i[4];
#pragma unroll
        for (int a = 0; a < 4; ++a) {
            float f9r = facr(9, a & 1), f9i = faci(9, a & 1);
            float f8r = facr(8, (a >> 1) & 1), f8i = faci(8, (a >> 1) & 1);
            t01r[a] = f9r * f8r - f9i * f8i;
            t01i[a] = f9r * f8i + f9i * f8r;
            float f7r = facr(7, a & 1), f7i = faci(7, a & 1);
            float f6r = facr(6, (a >> 1) & 1), f6i = faci(6, (a >> 1) & 1);
            t23r[a] = f7r * f6r - f7i * f6i;
            t23i[a] = f7r * f6i + f7i * f6r;
        }
        float prer[4], prei[4];
#pragma unroll
        for (int a = 0; a < 4; ++a) {
            prer[a] = hr * t01r[a] - hi * t01i[a];
            prei[a] = hr * t01i[a] + hi * t01r[a];
        }
#pragma unroll
        for (int j = 0; j < 16; ++j) {
            float rr = prer[j & 3] * t23r[j >> 2] - prei[j & 3] * t23i[j >> 2];
            float ii = prer[j & 3] * t23i[j >> 2] + prei[j & 3] * t23r[j >> 2];
            s[j] = rr;
            ship[pc][j * 64 + lane] = ii;   // conflict-free per j
        }
    }
    __syncthreads();
    if (comp == 1) {
#pragma unroll
        for (int j = 0; j < 16; ++j) s[j] = ship[pc][j * 64 + lane];
    }

    // ---- CZ-chain sign as XOR mask ----
    unsigned czm[16];
#pragma unroll
    for (int j = 0; j < 16; ++j) {
        unsigned i = ((unsigned)lane << 4) | (unsigned)j;
        czm[j] = (unsigned)(__popc(i & (i >> 1)) & 1) << 31;
    }

    // ---- QD layers (real arithmetic on this wave's component) ----
#pragma unroll 1
    for (int l = 0; l < QD; ++l) {
        const int base = l * NQ;
        float c[NQ], sn[NQ];
#pragma unroll
        for (int q = 0; q < NQ; ++q) {
            c[q]  = rlane(wcv, base + q);   // SGPR
            sn[q] = rlane(wsv, base + q);
        }

        intra_rot<1>(s, c[9], sn[9]);           // reg bits: wires 9..6
        intra_rot<2>(s, c[8], sn[8]);
        intra_rot<4>(s, c[7], sn[7]);
        intra_rot<8>(s, c[6], sn[6]);
        cross_rot<FX1, 1>(s, c[5], sn[5], lane);// lane bits 0..3: wires 5..2
        cross_rot<FX2, 2>(s, c[4], sn[4], lane);
        cross_rot<FX4, 4>(s, c[3], sn[3], lane);
        cross_rot<FX8, 8>(s, c[2], sn[2], lane);
#if HAVE_SWAP
        tr_b5b3(s);                             // wires 1,0 via transposes
        tr_b4b2(s);
        intra_rot<8>(s, c[0], sn[0]);
        intra_rot<4>(s, c[1], sn[1]);
        tr_b4b2(s);
        tr_b5b3(s);
#else
        cross_rot<FX32,32>(s, c[0], sn[0], lane);
        cross_rot<FX16,16>(s, c[1], sn[1], lane);
#endif
#pragma unroll
        for (int j = 0; j < 16; ++j)            // CZ: sign-bit xor
            s[j] = __uint_as_float(__float_as_uint(s[j]) ^ czm[j]);
    }

    // ---- expectations: this component's partial sums ----
    float myp = 0.f;
    {
        float e9 = wave_reduce(intra_exp<1>(s));
        float e8 = wave_reduce(intra_exp<2>(s));
        float e7 = wave_reduce(intra_exp<4>(s));
        float e6 = wave_reduce(intra_exp<8>(s));
        float e5 = wave_reduce(cross_exp<FX1>(s));
        float e4 = wave_reduce(cross_exp<FX2>(s));
        float e3 = wave_reduce(cross_exp<FX4>(s));
        float e2 = wave_reduce(cross_exp<FX8>(s));
        float e0, e1;
#if HAVE_SWAP
        tr_b5b3(s);
        tr_b4b2(s);
        e0 = wave_reduce(intra_exp<8>(s));
        e1 = wave_reduce(intra_exp<4>(s));
#else
        e0 = wave_reduce(cross_exp<FX32>(s));
        e1 = wave_reduce(cross_exp<FX16>(s));
#endif
        myp = (lane == 0) ? e0 : myp;
        myp = (lane == 1) ? e1 : myp;
        myp = (lane == 2) ? e2 : myp;
        myp = (lane == 3) ? e3 : myp;
        myp = (lane == 4) ? e4 : myp;
        myp = (lane == 5) ? e5 : myp;
        myp = (lane == 6) ? e6 : myp;
        myp = (lane == 7) ? e7 : myp;
        myp = (lane == 8) ? e8 : myp;
        myp = (lane == 9) ? e9 : myp;
    }

    // ---- couple re+im partials via LDS; odd wave stores ----
    if (comp == 0 && lane < NQ) partlds[pc][lane] = myp;
    __syncthreads();
    if (comp == 1 && lane < NQ)
        out[b * (NG * NQ) + g * NQ + lane] = myp + partlds[pc][lane];
}

extern "C" void kernel_launch(void* const* d_in, const int* in_sizes, int n_in,
                              void* d_out, int out_size, void* d_ws, size_t ws_size,
                              hipStream_t stream) {
    const float* noise = (const float*)d_in[0];   // (1024, 10) float32
    const float* qp    = (const float*)d_in[1];   // (4, 6, 10) float32
    float* out = (float*)d_out;                   // (1024, 40) float32

    const int nblocks = (NBATCH * NG) / 2;        // 2048 blocks x 4 waves
    qsim_kernel<<<nblocks, 256, 0, stream>>>(noise, qp, out);
}

// Round 8
// 99.513 us; speedup vs baseline: 1.0961x; 1.0961x over previous
//
#include <hip/hip_runtime.h>

#define NQ 10
#define NG 4
#define QD 6
#define NBATCH 1024
#define WPB 4   // waves per block; block = 4 batch samples of ONE generator

// 2^10 = 1024 amps; 64 lanes x 16 amps/lane, one circuit per wave.
// Flat index i: bit p (LSB) <-> wire q = 9-p (wire 0 = MSB, PennyLane order).
// i = lane*16 + j : bits 0..3 <- j (intra-lane), bits 4..9 <- lane bits 0..5.
// R8: pure-SCALAR state (sr[16], si[16]) — R3/R4 showed v2f does not cut
// VALU issue slots on CDNA4 (fp32 pk is not rate-doubling) and costs
// pack/unpack movs. DPP fetches bound_ctrl=1, single-use, written as
// mul+fma so GCNDPPCombine folds the dpp mov into the consumer.
// CZ = sign-bit XOR (R7-validated). permlane16/32_swap transposes for
// wires 0,1 (R6-validated). Weights via one lane-parallel sincos +
// readlane to SGPRs (R6-validated). NO min-waves launch bound (R7's
// (256,8) caused VGPR=32 + 14 MB of scratch spill traffic).

typedef unsigned u2v __attribute__((ext_vector_type(2)));

// ---------- DPP helpers ----------
template<int CTRL, int RM, int BM, bool BC>
__device__ __forceinline__ float dppmov(float x) {
    return __int_as_float(__builtin_amdgcn_update_dpp(
        0, __float_as_int(x), CTRL, RM, BM, BC));
}
// fetch DPPs: full permutations, bound_ctrl=1 (fusable into consumer VALU)
template<int CTRL>
__device__ __forceinline__ float dpp1(float x) { return dppmov<CTRL,0xF,0xF,true>(x); }
// xor1 = quad_perm{1,0,3,2}=0xB1; xor2 = quad_perm{2,3,0,1}=0x4E;
// xor4 = row_half_mirror(^7)=0x141 then quad_perm{3,2,1,0}(^3)=0x1B;
// xor8 = row_ror:8 = 0x128. (all validated R6/R7)

struct FX1 { static __device__ __forceinline__ float f(float x){ return dpp1<0xB1>(x); } };
struct FX2 { static __device__ __forceinline__ float f(float x){ return dpp1<0x4E>(x); } };
struct FX4 { static __device__ __forceinline__ float f(float x){ return dpp1<0x1B>(dpp1<0x141>(x)); } };
struct FX8 { static __device__ __forceinline__ float f(float x){ return dpp1<0x128>(x); } };
// fallbacks if permlane-swap builtins unavailable
struct FX16 {
    static __device__ __forceinline__ float f(float x){
        return __int_as_float(__builtin_amdgcn_ds_swizzle(__float_as_int(x), 0x401F));
    }
};
struct FX32 {
    static __device__ __forceinline__ float f(float x){ return __shfl_xor(x, 32, 64); }
};

__device__ __forceinline__ float rlane(float v, int idx) {
    return __int_as_float(__builtin_amdgcn_readlane(__float_as_int(v), idx));
}

// ---------- gfx950 permlane swap transposes (validated R6/R7) ----------
#if __has_builtin(__builtin_amdgcn_permlane32_swap) && __has_builtin(__builtin_amdgcn_permlane16_swap)
#define HAVE_SWAP 1
__device__ __forceinline__ void plswap32(float &a, float &b) {
    u2v r = __builtin_amdgcn_permlane32_swap(__float_as_uint(a), __float_as_uint(b), false, false);
    a = __uint_as_float(r.x); b = __uint_as_float(r.y);
}
__device__ __forceinline__ void plswap16(float &a, float &b) {
    u2v r = __builtin_amdgcn_permlane16_swap(__float_as_uint(a), __float_as_uint(b), false, false);
    a = __uint_as_float(r.x); b = __uint_as_float(r.y);
}
// transpose lane-bit5 <-> reg-bit3
__device__ __forceinline__ void tr_b5b3(float (&s)[16]) {
#pragma unroll
    for (int j = 0; j < 8; ++j) plswap32(s[j], s[j + 8]);
}
// transpose lane-bit4 <-> reg-bit2
__device__ __forceinline__ void tr_b4b2(float (&s)[16]) {
#pragma unroll
    for (int jj = 0; jj < 8; ++jj) {
        const int j = (jj & 3) | ((jj >> 2) << 3);   // 0,1,2,3,8,9,10,11
        plswap16(s[j], s[j + 4]);
    }
}
#else
#define HAVE_SWAP 0
#endif

// wave-wide sum broadcast (validated R3..R7)
__device__ __forceinline__ float wave_reduce(float x) {
    x += dppmov<0x111,0xF,0xF,true >(x);   // row_shr:1
    x += dppmov<0x112,0xF,0xF,true >(x);   // row_shr:2
    x += dppmov<0x114,0xF,0xF,true >(x);   // row_shr:4
    x += dppmov<0x118,0xF,0xF,true >(x);   // row_shr:8
    x += dppmov<0x142,0xA,0xF,false>(x);   // row_bcast15
    x += dppmov<0x143,0xC,0xF,false>(x);   // row_bcast31
    return __int_as_float(__builtin_amdgcn_readlane(__float_as_int(x), 63));
}

template<int M>
__device__ __forceinline__ void intra_rot1(float (&s)[16], float c, float sn) {
#pragma unroll
    for (int j = 0; j < 16; ++j)
        if ((j & M) == 0) {
            const int k = j | M;
            float v0 = s[j], v1 = s[k];
            s[j] = c * v0 - sn * v1;   // mul + fma(-sn)
            s[k] = sn * v0 + c * v1;   // mul + fma
        }
}

// x' = c*x + sv*dpp(x); written so the dpp feeds a single fma (combinable)
template<class PF, int LM>
__device__ __forceinline__ void cross_rot(float (&sr)[16], float (&si)[16],
                                          float c, float sn, int lane) {
    const float sv = (lane & LM) ? sn : -sn;
#pragma unroll
    for (int j = 0; j < 16; ++j) {
        float pr = PF::f(sr[j]);
        sr[j] = c * sr[j] + sv * pr;
        float pi = PF::f(si[j]);
        si[j] = c * si[j] + sv * pi;
    }
}

template<class PF>
__device__ __forceinline__ float cross_exp(const float (&sr)[16], const float (&si)[16]) {
    float a = 0.f;
#pragma unroll
    for (int j = 0; j < 16; ++j) {
        a += sr[j] * PF::f(sr[j]);
        a += si[j] * PF::f(si[j]);
    }
    return a;
}

template<int M>
__device__ __forceinline__ float intra_exp(const float (&sr)[16], const float (&si)[16]) {
    float a = 0.f;
#pragma unroll
    for (int j = 0; j < 16; ++j)
        a += sr[j] * sr[j ^ M] + si[j] * si[j ^ M];
    return a;
}

__global__ __launch_bounds__(64 * WPB) void qsim_kernel(
    const float* __restrict__ noise,     // (NBATCH, NQ)
    const float* __restrict__ qp,        // (NG, QD, NQ)
    float* __restrict__ out)             // (NBATCH, NG*NQ)
{
    const int wave = threadIdx.x >> 6;
    const int lane = threadIdx.x & 63;
    const int g    = blockIdx.x & 3;                  // block-uniform
    const int b    = (blockIdx.x >> 2) * WPB + wave;  // batch sample per wave

    // ---- weight angles: lane-parallel sincos once, readlane per layer ----
    float wcv, wsv;
    {
        const int widx = (lane < QD * NQ) ? lane : 0;
        __sincosf(0.5f * qp[g * (QD * NQ) + widx], &wsv, &wcv);
    }

    // ---- init: product state RX(t)RY(t)|0> per qubit ----
    float sr[16], si[16];
    {
        float nc[NQ], ns[NQ];
#pragma unroll
        for (int q = 0; q < NQ; ++q)
            __sincosf(0.5f * noise[b * NQ + q], &ns[q], &nc[q]);

        // per-qubit factor: bit=0 -> (c^2,-s^2), bit=1 -> (cs,-cs)
        auto facr = [&](int q, int bit) { return bit ? nc[q]*ns[q] : nc[q]*nc[q]; };
        auto faci = [&](int q, int bit) { return bit ? -nc[q]*ns[q] : -ns[q]*ns[q]; };

        // lane-determined product over lane bits 0..5 (wires 5..0)
        float hr = 1.f, hi = 0.f;
#pragma unroll
        for (int p = 4; p <= 9; ++p) {
            const int q = NQ - 1 - p, bit = (lane >> (p - 4)) & 1;
            float fr = facr(q, bit), fi = faci(q, bit);
            float tr = hr * fr - hi * fi;
            float ti = hr * fi + hi * fr;
            hr = tr; hi = ti;
        }
        // factor tree over reg bits: t01 = wires 9,8 ; t23 = wires 7,6
        float t01r[4], t01i[4], t23r[4], t23i[4];
#pragma unroll
        for (int a = 0; a < 4; ++a) {
            float f9r = facr(9, a & 1), f9i = faci(9, a & 1);
            float f8r = facr(8, (a >> 1) & 1), f8i = faci(8, (a >> 1) & 1);
            t01r[a] = f9r * f8r - f9i * f8i;
            t01i[a] = f9r * f8i + f9i * f8r;
            float f7r = facr(7, a & 1), f7i = faci(7, a & 1);
            float f6r = facr(6, (a >> 1) & 1), f6i = faci(6, (a >> 1) & 1);
            t23r[a] = f7r * f6r - f7i * f6i;
            t23i[a] = f7r * f6i + f7i * f6r;
        }
        float prer[4], prei[4];
#pragma unroll
        for (int a = 0; a < 4; ++a) {
            prer[a] = hr * t01r[a] - hi * t01i[a];
            prei[a] = hr * t01i[a] + hi * t01r[a];
        }
#pragma unroll
        for (int j = 0; j < 16; ++j) {
            sr[j] = prer[j & 3] * t23r[j >> 2] - prei[j & 3] * t23i[j >> 2];
            si[j] = prer[j & 3] * t23i[j >> 2] + prei[j & 3] * t23r[j >> 2];
        }
    }

    // ---- CZ-chain sign as XOR mask (R7-validated) ----
    unsigned czm[16];
#pragma unroll
    for (int j = 0; j < 16; ++j) {
        unsigned i = ((unsigned)lane << 4) | (unsigned)j;
        czm[j] = (unsigned)(__popc(i & (i >> 1)) & 1) << 31;
    }

    // ---- QD layers ----
#pragma unroll 1
    for (int l = 0; l < QD; ++l) {
        const int base = l * NQ;
        float c[NQ], sn[NQ];
#pragma unroll
        for (int q = 0; q < NQ; ++q) {
            c[q]  = rlane(wcv, base + q);   // SGPR
            sn[q] = rlane(wsv, base + q);
        }

        // reg-bit wires 9..6 (intra)
        intra_rot1<1>(sr, c[9], sn[9]); intra_rot1<1>(si, c[9], sn[9]);
        intra_rot1<2>(sr, c[8], sn[8]); intra_rot1<2>(si, c[8], sn[8]);
        intra_rot1<4>(sr, c[7], sn[7]); intra_rot1<4>(si, c[7], sn[7]);
        intra_rot1<8>(sr, c[6], sn[6]); intra_rot1<8>(si, c[6], sn[6]);
        // lane-bit wires 5..2 (DPP cross, fused fetch)
        cross_rot<FX1, 1>(sr, si, c[5], sn[5], lane);
        cross_rot<FX2, 2>(sr, si, c[4], sn[4], lane);
        cross_rot<FX4, 4>(sr, si, c[3], sn[3], lane);
        cross_rot<FX8, 8>(sr, si, c[2], sn[2], lane);
        // wires 1,0 (lane bits 4,5) via permlane transposes
#if HAVE_SWAP
        tr_b5b3(sr); tr_b5b3(si);
        tr_b4b2(sr); tr_b4b2(si);
        intra_rot1<8>(sr, c[0], sn[0]); intra_rot1<8>(si, c[0], sn[0]);
        intra_rot1<4>(sr, c[1], sn[1]); intra_rot1<4>(si, c[1], sn[1]);
        tr_b4b2(sr); tr_b4b2(si);
        tr_b5b3(sr); tr_b5b3(si);
#else
        cross_rot<FX32,32>(sr, si, c[0], sn[0], lane);
        cross_rot<FX16,16>(sr, si, c[1], sn[1], lane);
#endif
        // CZ diagonal: sign-bit xor
#pragma unroll
        for (int j = 0; j < 16; ++j) {
            sr[j] = __uint_as_float(__float_as_uint(sr[j]) ^ czm[j]);
            si[j] = __uint_as_float(__float_as_uint(si[j]) ^ czm[j]);
        }
    }

    // ---- expectations <X_q> ----
    float outval = 0.f;
    {
        float e9 = wave_reduce(intra_exp<1>(sr, si));
        float e8 = wave_reduce(intra_exp<2>(sr, si));
        float e7 = wave_reduce(intra_exp<4>(sr, si));
        float e6 = wave_reduce(intra_exp<8>(sr, si));
        float e5 = wave_reduce(cross_exp<FX1>(sr, si));
        float e4 = wave_reduce(cross_exp<FX2>(sr, si));
        float e3 = wave_reduce(cross_exp<FX4>(sr, si));
        float e2 = wave_reduce(cross_exp<FX8>(sr, si));
        float e0, e1;
#if HAVE_SWAP
        tr_b5b3(sr); tr_b5b3(si);
        tr_b4b2(sr); tr_b4b2(si);
        e0 = wave_reduce(intra_exp<8>(sr, si));
        e1 = wave_reduce(intra_exp<4>(sr, si));
#else
        e0 = wave_reduce(cross_exp<FX32>(sr, si));
        e1 = wave_reduce(cross_exp<FX16>(sr, si));
#endif
        outval = (lane == 0) ? e0 : outval;
        outval = (lane == 1) ? e1 : outval;
        outval = (lane == 2) ? e2 : outval;
        outval = (lane == 3) ? e3 : outval;
        outval = (lane == 4) ? e4 : outval;
        outval = (lane == 5) ? e5 : outval;
        outval = (lane == 6) ? e6 : outval;
        outval = (lane == 7) ? e7 : outval;
        outval = (lane == 8) ? e8 : outval;
        outval = (lane == 9) ? e9 : outval;
    }

    if (lane < NQ)
        out[b * (NG * NQ) + g * NQ + lane] = outval;
}

extern "C" void kernel_launch(void* const* d_in, const int* in_sizes, int n_in,
                              void* d_out, int out_size, void* d_ws, size_t ws_size,
                              hipStream_t stream) {
    const float* noise = (const float*)d_in[0];   // (1024, 10) float32
    const float* qp    = (const float*)d_in[1];   // (4, 6, 10) float32
    float* out = (float*)d_out;                   // (1024, 40) float32

    const int nblocks = (NBATCH * NG) / WPB;      // 1024 blocks x 4 waves
    qsim_kernel<<<nblocks, 64 * WPB, 0, stream>>>(noise, qp, out);
}

// Round 9
// 87.614 us; speedup vs baseline: 1.2450x; 1.1358x over previous
//
#include <hip/hip_runtime.h>

#define NQ 10
#define NG 4
#define QD 6
#define NBATCH 1024
#define WPB 4   // waves per block; block = 4 batch samples of ONE generator

// 2^10 = 1024 amps; 64 lanes x 16 amps/lane, one circuit per wave.
// Flat index i: bit p (LSB) <-> wire q = 9-p (wire 0 = MSB, PennyLane order).
// i = lane*16 + j : bits 0..3 <- j (intra-lane), bits 4..9 <- lane bits 0..5.
// R9: tangent-form rotations. RY(th) = c*(I - t*J), t=tan(th/2); apply only
// (I - t*J) (intra pair: 2 fma; cross: 1 fmac with DPP-src partner fetch),
// accumulate scale = PROD c over all 60 layer angles once (wave butterfly
// product), multiply expectations by scale^2 at the end. Weights uniform[0,1]
// -> t <= 0.55, safe. CZ = sign-bit XOR with 4 precomputed masks (parity
// decomposition), freeing 12 VGPRs vs czm[16]. launch_bounds(256,2) lifts the
// VGPR cap (grid = 4 waves/SIMD, so <=128 VGPR is occupancy-free) so the
// in-place rotation pairs rename instead of emitting movs.

typedef unsigned u2v __attribute__((ext_vector_type(2)));

// ---------- DPP helpers ----------
template<int CTRL, int RM, int BM, bool BC>
__device__ __forceinline__ float dppmov(float x) {
    return __int_as_float(__builtin_amdgcn_update_dpp(
        0, __float_as_int(x), CTRL, RM, BM, BC));
}
template<int CTRL>
__device__ __forceinline__ float dpp1(float x) { return dppmov<CTRL,0xF,0xF,true>(x); }
// xor1 = quad_perm{1,0,3,2}=0xB1; xor2 = quad_perm{2,3,0,1}=0x4E;
// xor4 = 0x141(row_half_mirror,^7) then 0x1B(quad rev,^3); xor8 = row_ror:8 = 0x128.

struct FX1 { static __device__ __forceinline__ float f(float x){ return dpp1<0xB1>(x); } };
struct FX2 { static __device__ __forceinline__ float f(float x){ return dpp1<0x4E>(x); } };
struct FX4 { static __device__ __forceinline__ float f(float x){ return dpp1<0x1B>(dpp1<0x141>(x)); } };
struct FX8 { static __device__ __forceinline__ float f(float x){ return dpp1<0x128>(x); } };
struct FX16 {
    static __device__ __forceinline__ float f(float x){
        return __int_as_float(__builtin_amdgcn_ds_swizzle(__float_as_int(x), 0x401F));
    }
};
struct FX32 {
    static __device__ __forceinline__ float f(float x){ return __shfl_xor(x, 32, 64); }
};

__device__ __forceinline__ float rlane(float v, int idx) {
    return __int_as_float(__builtin_amdgcn_readlane(__float_as_int(v), idx));
}

// ---------- gfx950 permlane swap transposes (validated R6/R7/R8) ----------
#if __has_builtin(__builtin_amdgcn_permlane32_swap) && __has_builtin(__builtin_amdgcn_permlane16_swap)
#define HAVE_SWAP 1
__device__ __forceinline__ void plswap32(float &a, float &b) {
    u2v r = __builtin_amdgcn_permlane32_swap(__float_as_uint(a), __float_as_uint(b), false, false);
    a = __uint_as_float(r.x); b = __uint_as_float(r.y);
}
__device__ __forceinline__ void plswap16(float &a, float &b) {
    u2v r = __builtin_amdgcn_permlane16_swap(__float_as_uint(a), __float_as_uint(b), false, false);
    a = __uint_as_float(r.x); b = __uint_as_float(r.y);
}
__device__ __forceinline__ void tr_b5b3(float (&s)[16]) {     // lane5 <-> reg3
#pragma unroll
    for (int j = 0; j < 8; ++j) plswap32(s[j], s[j + 8]);
}
__device__ __forceinline__ void tr_b4b2(float (&s)[16]) {     // lane4 <-> reg2
#pragma unroll
    for (int jj = 0; jj < 8; ++jj) {
        const int j = (jj & 3) | ((jj >> 2) << 3);   // 0,1,2,3,8,9,10,11
        plswap16(s[j], s[j + 4]);
    }
}
#else
#define HAVE_SWAP 0
#endif

// wave-wide sum broadcast (validated R3..R8)
__device__ __forceinline__ float wave_reduce(float x) {
    x += dppmov<0x111,0xF,0xF,true >(x);
    x += dppmov<0x112,0xF,0xF,true >(x);
    x += dppmov<0x114,0xF,0xF,true >(x);
    x += dppmov<0x118,0xF,0xF,true >(x);
    x += dppmov<0x142,0xA,0xF,false>(x);
    x += dppmov<0x143,0xC,0xF,false>(x);
    return __int_as_float(__builtin_amdgcn_readlane(__float_as_int(x), 63));
}

// wave-wide product via full butterfly (all fetches are total permutations;
// bound_ctrl-zero never exposed). Result identical in all lanes.
__device__ __forceinline__ float wave_product(float x) {
    x *= dpp1<0xB1>(x);                      // xor1
    x *= dpp1<0x4E>(x);                      // xor2
    x *= dpp1<0x1B>(dpp1<0x141>(x));         // xor4
    x *= dpp1<0x128>(x);                     // xor8
    x *= FX16::f(x);                         // xor16 (one-time swizzle)
    x *= FX32::f(x);                         // xor32 (one-time shfl)
    return x;
}

// (I - t*J) on an intra-register pair: 2 fma, SSA-renamed (no movs w/ headroom)
template<int M>
__device__ __forceinline__ void intra_rot_t(float (&s)[16], float t) {
#pragma unroll
    for (int j = 0; j < 16; ++j)
        if ((j & M) == 0) {
            const int k = j | M;
            float v0 = s[j], v1 = s[k];
            s[j] = fmaf(-t, v1, v0);
            s[k] = fmaf( t, v0, v1);
        }
}

// (I - t*J) cross-lane: x += sv * dpp(x), sv = +-t by lane bit (sign
// convention validated R1..R8). DPP feeds fmac src0 -> combinable.
template<class PF, int LM>
__device__ __forceinline__ void cross_rot_t(float (&sr)[16], float (&si)[16],
                                            float t, int lane) {
    const float sv = (lane & LM) ? t : -t;
#pragma unroll
    for (int j = 0; j < 16; ++j) {
        sr[j] = fmaf(PF::f(sr[j]), sv, sr[j]);
        si[j] = fmaf(PF::f(si[j]), sv, si[j]);
    }
}

template<class PF>
__device__ __forceinline__ float cross_exp(const float (&sr)[16], const float (&si)[16]) {
    float a = 0.f;
#pragma unroll
    for (int j = 0; j < 16; ++j) {
        a = fmaf(PF::f(sr[j]), sr[j], a);
        a = fmaf(PF::f(si[j]), si[j], a);
    }
    return a;
}

template<int M>
__device__ __forceinline__ float intra_exp(const float (&sr)[16], const float (&si)[16]) {
    float a = 0.f;
#pragma unroll
    for (int j = 0; j < 16; ++j)
        a += sr[j] * sr[j ^ M] + si[j] * si[j ^ M];
    return a;
}

__global__ __launch_bounds__(256, 2) void qsim_kernel(
    const float* __restrict__ noise,     // (NBATCH, NQ)
    const float* __restrict__ qp,        // (NG, QD, NQ)
    float* __restrict__ out)             // (NBATCH, NG*NQ)
{
    const int wave = threadIdx.x >> 6;
    const int lane = threadIdx.x & 63;
    const int g    = blockIdx.x & 3;                  // block-uniform
    const int b    = (blockIdx.x >> 2) * WPB + wave;  // batch sample per wave

    // ---- weights: lane-parallel sincos once; t = tan, scale = prod(c) ----
    float wt, scale2;
    {
        const int widx = (lane < QD * NQ) ? lane : 0;
        float sv, cv;
        __sincosf(0.5f * qp[g * (QD * NQ) + widx], &sv, &cv);
        wt = sv / cv;                                    // t in [0, 0.55]
        float cvc = (lane < QD * NQ) ? cv : 1.0f;        // identity padding
        float p = wave_product(cvc);                     // prod of 60 cosines
        scale2 = p * p;
    }

    // ---- init: product state RX(t)RY(t)|0> per qubit (exact, R8-validated) --
    float sr[16], si[16];
    {
        float nc[NQ], ns[NQ];
#pragma unroll
        for (int q = 0; q < NQ; ++q)
            __sincosf(0.5f * noise[b * NQ + q], &ns[q], &nc[q]);

        auto facr = [&](int q, int bit) { return bit ? nc[q]*ns[q] : nc[q]*nc[q]; };
        auto faci = [&](int q, int bit) { return bit ? -nc[q]*ns[q] : -ns[q]*ns[q]; };

        float hr = 1.f, hi = 0.f;
#pragma unroll
        for (int p = 4; p <= 9; ++p) {
            const int q = NQ - 1 - p, bit = (lane >> (p - 4)) & 1;
            float fr = facr(q, bit), fi = faci(q, bit);
            float tr = hr * fr - hi * fi;
            float ti = hr * fi + hi * fr;
            hr = tr; hi = ti;
        }
        float t01r[4], t01i[4], t23r[4], t23i[4];
#pragma unroll
        for (int a = 0; a < 4; ++a) {
            float f9r = facr(9, a & 1), f9i = faci(9, a & 1);
            float f8r = facr(8, (a >> 1) & 1), f8i = faci(8, (a >> 1) & 1);
            t01r[a] = f9r * f8r - f9i * f8i;
            t01i[a] = f9r * f8i + f9i * f8r;
            float f7r = facr(7, a & 1), f7i = faci(7, a & 1);
            float f6r = facr(6, (a >> 1) & 1), f6i = faci(6, (a >> 1) & 1);
            t23r[a] = f7r * f6r - f7i * f6i;
            t23i[a] = f7r * f6i + f7i * f6r;
        }
        float prer[4], prei[4];
#pragma unroll
        for (int a = 0; a < 4; ++a) {
            prer[a] = hr * t01r[a] - hi * t01i[a];
            prei[a] = hr * t01i[a] + hi * t01r[a];
        }
#pragma unroll
        for (int j = 0; j < 16; ++j) {
            sr[j] = prer[j & 3] * t23r[j >> 2] - prei[j & 3] * t23i[j >> 2];
            si[j] = prer[j & 3] * t23i[j >> 2] + prei[j & 3] * t23r[j >> 2];
        }
    }

    // ---- CZ sign masks: parity decomposition of popc(i & (i>>1)) ----
    // i = lane*16+j. Pairs: within-j (compile-time), (j bit3, lane bit0),
    // within-lane (runtime, 1 value). -> 4 mask regs instead of czm[16].
    unsigned mE, mEn, mO, mOn;
    {
        unsigned par_l = (unsigned)(__popc(lane & (lane >> 1)) & 1) << 31;
        mE  = par_l;                               // j<8,  even j-parity
        mEn = mE ^ 0x80000000u;                    // j<8,  odd  j-parity
        mO  = mE ^ ((unsigned)(lane & 1) << 31);   // j>=8, even j-parity
        mOn = mO ^ 0x80000000u;                    // j>=8, odd  j-parity
    }

    // ---- QD layers (tangent-form) ----
#pragma unroll 1
    for (int l = 0; l < QD; ++l) {
        const int base = l * NQ;
        float t[NQ];
#pragma unroll
        for (int q = 0; q < NQ; ++q) t[q] = rlane(wt, base + q);

        intra_rot_t<1>(sr, t[9]); intra_rot_t<1>(si, t[9]);   // reg-bit wires
        intra_rot_t<2>(sr, t[8]); intra_rot_t<2>(si, t[8]);
        intra_rot_t<4>(sr, t[7]); intra_rot_t<4>(si, t[7]);
        intra_rot_t<8>(sr, t[6]); intra_rot_t<8>(si, t[6]);
        cross_rot_t<FX1, 1>(sr, si, t[5], lane);              // lane-bit wires
        cross_rot_t<FX2, 2>(sr, si, t[4], lane);
        cross_rot_t<FX4, 4>(sr, si, t[3], lane);
        cross_rot_t<FX8, 8>(sr, si, t[2], lane);
#if HAVE_SWAP
        tr_b5b3(sr); tr_b5b3(si);                             // wires 1,0
        tr_b4b2(sr); tr_b4b2(si);
        intra_rot_t<8>(sr, t[0]); intra_rot_t<8>(si, t[0]);
        intra_rot_t<4>(sr, t[1]); intra_rot_t<4>(si, t[1]);
        tr_b4b2(sr); tr_b4b2(si);
        tr_b5b3(sr); tr_b5b3(si);
#else
        cross_rot_t<FX32,32>(sr, si, t[0], lane);
        cross_rot_t<FX16,16>(sr, si, t[1], lane);
#endif
        // CZ diagonal: sign-bit xor, compile-time mask select per j
#pragma unroll
        for (int j = 0; j < 16; ++j) {
            const bool jpar = (__popc(j & (j >> 1)) & 1) != 0;   // folds (j const)
            const unsigned m = (j & 8) ? (jpar ? mOn : mO) : (jpar ? mEn : mE);
            sr[j] = __uint_as_float(__float_as_uint(sr[j]) ^ m);
            si[j] = __uint_as_float(__float_as_uint(si[j]) ^ m);
        }
    }

    // ---- expectations <X_q>, scaled by (prod c)^2 ----
    float outval = 0.f;
    {
        float e9 = wave_reduce(intra_exp<1>(sr, si));
        float e8 = wave_reduce(intra_exp<2>(sr, si));
        float e7 = wave_reduce(intra_exp<4>(sr, si));
        float e6 = wave_reduce(intra_exp<8>(sr, si));
        float e5 = wave_reduce(cross_exp<FX1>(sr, si));
        float e4 = wave_reduce(cross_exp<FX2>(sr, si));
        float e3 = wave_reduce(cross_exp<FX4>(sr, si));
        float e2 = wave_reduce(cross_exp<FX8>(sr, si));
        float e0, e1;
#if HAVE_SWAP
        tr_b5b3(sr); tr_b5b3(si);
        tr_b4b2(sr); tr_b4b2(si);
        e0 = wave_reduce(intra_exp<8>(sr, si));
        e1 = wave_reduce(intra_exp<4>(sr, si));
#else
        e0 = wave_reduce(cross_exp<FX32>(sr, si));
        e1 = wave_reduce(cross_exp<FX16>(sr, si));
#endif
        outval = (lane == 0) ? e0 : outval;
        outval = (lane == 1) ? e1 : outval;
        outval = (lane == 2) ? e2 : outval;
        outval = (lane == 3) ? e3 : outval;
        outval = (lane == 4) ? e4 : outval;
        outval = (lane == 5) ? e5 : outval;
        outval = (lane == 6) ? e6 : outval;
        outval = (lane == 7) ? e7 : outval;
        outval = (lane == 8) ? e8 : outval;
        outval = (lane == 9) ? e9 : outval;
    }

    if (lane < NQ)
        out[b * (NG * NQ) + g * NQ + lane] = outval * scale2;
}

extern "C" void kernel_launch(void* const* d_in, const int* in_sizes, int n_in,
                              void* d_out, int out_size, void* d_ws, size_t ws_size,
                              hipStream_t stream) {
    const float* noise = (const float*)d_in[0];   // (1024, 10) float32
    const float* qp    = (const float*)d_in[1];   // (4, 6, 10) float32
    float* out = (float*)d_out;                   // (1024, 40) float32

    const int nblocks = (NBATCH * NG) / WPB;      // 1024 blocks x 4 waves
    qsim_kernel<<<nblocks, 64 * WPB, 0, stream>>>(noise, qp, out);
}